// Round 3
// baseline (299.439 us; speedup 1.0000x reference)
//
#include <hip/hip_runtime.h>
#include <hip/hip_bf16.h>
#include <stdint.h>

#define M_DIM 8192
#define N_DIM 4096
#define K_DIM 4096
#define BM 256
#define BN 256
#define BK2 64
#define NT2 (K_DIM / BK2)   // 64 K-tiles
#define THREADS 512
#define NBLOCKS_VQ (N_DIM * K_DIM / 16)

#define TILE_B 32768        // one A (or B) K-tile: 256 rows x 64 cols x 2B
#define BBASE  65536        // B buffers start at 64KB
#define SMEM_BYTES 131072

typedef short bf16x8 __attribute__((ext_vector_type(8)));
typedef float f32x4 __attribute__((ext_vector_type(4)));
typedef unsigned short ushort_t;
typedef ushort_t ushort8 __attribute__((ext_vector_type(8)));

#define GLOBAL_AS __attribute__((address_space(1)))
#define LDS_AS __attribute__((address_space(3)))

__device__ __forceinline__ ushort_t f2bf(float f) {
  union { float f; uint32_t u; } v; v.f = f;
  uint32_t u = v.u;
  return (ushort_t)((u + 0x7FFFu + ((u >> 16) & 1u)) >> 16);
}

// ---------------- dequant: W[j][k] = coarse[cl[b]] + res[rl[b]], block b of 16 elems
__global__ __launch_bounds__(256) void dequant_w(
    const float* __restrict__ cc, const int* __restrict__ cl,
    const float* __restrict__ rc, const int* __restrict__ rl,
    ushort_t* __restrict__ wout) {
  int b = blockIdx.x * 256 + threadIdx.x;
  int ci = cl[b];
  int ri = rl[b];
  const float4* c4 = (const float4*)(cc + (size_t)ci * 16);
  const float4* r4 = (const float4*)(rc + (size_t)ri * 16);
  float s[16];
#pragma unroll
  for (int p = 0; p < 4; ++p) {
    float4 a = c4[p];
    float4 r = r4[p];
    s[p * 4 + 0] = a.x + r.x;
    s[p * 4 + 1] = a.y + r.y;
    s[p * 4 + 2] = a.z + r.z;
    s[p * 4 + 3] = a.w + r.w;
  }
  ushort8 o0, o1;
#pragma unroll
  for (int j = 0; j < 8; ++j) o0[j] = f2bf(s[j]);
#pragma unroll
  for (int j = 0; j < 8; ++j) o1[j] = f2bf(s[8 + j]);
  ushort8* dst = (ushort8*)(wout + (size_t)b * 16);
  dst[0] = o0;
  dst[1] = o1;
}

// ---------------- x fp32 -> bf16
__global__ __launch_bounds__(256) void cvt_x_bf16(const float* __restrict__ x,
                                                  ushort_t* __restrict__ xb) {
  size_t i = (size_t)blockIdx.x * 256 + threadIdx.x;  // 8 elems each
  const float4* p = (const float4*)x + i * 2;
  float4 a = p[0];
  float4 b = p[1];
  ushort8 o;
  o[0] = f2bf(a.x); o[1] = f2bf(a.y); o[2] = f2bf(a.z); o[3] = f2bf(a.w);
  o[4] = f2bf(b.x); o[5] = f2bf(b.y); o[6] = f2bf(b.z); o[7] = f2bf(b.w);
  ((ushort8*)xb)[i] = o;
}

// stage one K-tile (A 256x64 + B 256x64 bf16) into buffer `buf` (8 loads/thread).
// gA0/gB0 already carry the inverse-swizzled source column.
__device__ __forceinline__ void stage_tile(char* smem,
    const ushort_t* gA0, const ushort_t* gB0, int wbase, int tile, int buf) {
  const ushort_t* ga = gA0 + (size_t)tile * BK2;
  const ushort_t* gb = gB0 + (size_t)tile * BK2;
  char* la = smem + buf * TILE_B + wbase;
  char* lb = smem + BBASE + buf * TILE_B + wbase;
#pragma unroll
  for (int r = 0; r < 4; ++r) {
    __builtin_amdgcn_global_load_lds(
        (const GLOBAL_AS void*)(ga + (size_t)(r * 64) * K_DIM),
        (LDS_AS void*)(la + r * 8192), 16, 0, 0);
    __builtin_amdgcn_global_load_lds(
        (const GLOBAL_AS void*)(gb + (size_t)(r * 64) * K_DIM),
        (LDS_AS void*)(lb + r * 8192), 16, 0, 0);
  }
}

template<int VM, bool ISSUE>
__device__ __forceinline__ void kstep(char* smem,
    const ushort_t* gA0, const ushort_t* gB0, int wbase,
    int aBase, int bBase, f32x4 (&acc)[8][4], int t, int buf) {
  // counted vmcnt: tile t's 8 loads done; tile t+1's 8 stay in flight
  if constexpr (VM == 8) asm volatile("s_waitcnt vmcnt(8)" ::: "memory");
  else asm volatile("s_waitcnt vmcnt(0)" ::: "memory");
  __builtin_amdgcn_s_barrier();
  __builtin_amdgcn_sched_barrier(0);

  const ushort_t* aB = (const ushort_t*)(smem + buf * TILE_B) + aBase;
  const ushort_t* bB = (const ushort_t*)(smem + BBASE + buf * TILE_B) + bBase;

#pragma unroll
  for (int kk = 0; kk < 2; ++kk) {
    bf16x8 b[4], a[8];
#pragma unroll
    for (int n = 0; n < 4; ++n) b[n] = *(const bf16x8*)(bB + kk * 32 + n * 1024);
#pragma unroll
    for (int m = 0; m < 8; ++m) a[m] = *(const bf16x8*)(aB + kk * 32 + m * 1024);
    __builtin_amdgcn_s_setprio(1);
#pragma unroll
    for (int m = 0; m < 8; ++m)
#pragma unroll
      for (int n = 0; n < 4; ++n)
        acc[m][n] = __builtin_amdgcn_mfma_f32_16x16x32_bf16(a[m], b[n], acc[m][n], 0, 0, 0);
    __builtin_amdgcn_s_setprio(0);
  }
  __builtin_amdgcn_s_barrier();          // all waves done reading buf
  __builtin_amdgcn_sched_barrier(0);
  if constexpr (ISSUE)
    stage_tile(smem, gA0, gB0, wbase, t + 2, buf);  // overwrite just-freed buffer
}

// C[M][N] = A[M][K] * B[N][K]^T + bias; 256x256, BK=64, st_16x32 swizzle, 2-deep
__global__ __launch_bounds__(THREADS, 2) void gemm_bf16(
    const ushort_t* __restrict__ A, const ushort_t* __restrict__ B,
    const float* __restrict__ bias, float* __restrict__ C) {
  extern __shared__ char smem[];

  const int nwg = (M_DIM / BM) * (N_DIM / BN);  // 512, %8==0 -> bijective swizzle
  int bid = blockIdx.x;
  int swz = (bid & 7) * (nwg >> 3) + (bid >> 3);
  int bx = swz & 15;            // 16 N-tiles
  int by = swz >> 4;            // 32 M-tiles
  const int tileM = by * BM;
  const int tileN = bx * BN;

  const int tid = threadIdx.x;
  const int lane = tid & 63;
  const int wave = tid >> 6;
  const int wr = wave >> 2;     // 0..1 -> M offset wr*128
  const int wc = wave & 3;      // 0..3 -> N offset wc*64

  // staging: LDS linear byte tid*16 (+r*8192) = row tid>>3, 16B-slot tid&7.
  // st_16x32: read at (row, colByte cb) accesses cb ^ ((row&4)<<3), so the
  // linear slot s must hold source col group s ^ (2*((row>>2)&1)).
  int srow = tid >> 3;          // 0..63 (round r adds 64)
  int slot = tid & 7;
  int scol = ((slot ^ ((((unsigned)srow >> 2) & 1) << 1)) << 3);
  const ushort_t* gA0 = A + (size_t)(tileM + srow) * K_DIM + scol;
  const ushort_t* gB0 = B + (size_t)(tileN + srow) * K_DIM + scol;
  const int wbase = wave << 10;  // wave-uniform LDS base; HW appends lane*16

  // fragment read offsets (elems): row*64 + ((kk*32 + g*8) ^ ((lrow&4)<<2))
  const int lrow = lane & 15;
  const int g8 = (lane >> 4) << 3;               // k sub-offset 0,8,16,24
  const int kx = g8 ^ ((lrow & 4) << 2);         // st_16x32 read swizzle
  const int aBase = (wr * 128 + lrow) * 64 + kx;
  const int bBase = (wc * 64 + lrow) * 64 + kx;

  f32x4 acc[8][4];
#pragma unroll
  for (int m = 0; m < 8; ++m)
#pragma unroll
    for (int n = 0; n < 4; ++n) acc[m][n] = (f32x4)0.0f;

  // prologue: fill both buffers
  stage_tile(smem, gA0, gB0, wbase, 0, 0);
  stage_tile(smem, gA0, gB0, wbase, 1, 1);

  for (int tb = 0; tb < 31; ++tb) {   // t = 0..61
    kstep<8, true>(smem, gA0, gB0, wbase, aBase, bBase, acc, 2 * tb, 0);
    kstep<8, true>(smem, gA0, gB0, wbase, aBase, bBase, acc, 2 * tb + 1, 1);
  }
  kstep<8, false>(smem, gA0, gB0, wbase, aBase, bBase, acc, 62, 0);
  kstep<0, false>(smem, gA0, gB0, wbase, aBase, bBase, acc, 63, 1);

  // epilogue: C/D layout col = lane&15, row = (lane>>4)*4 + reg
  const int orow = tileM + wr * 128 + ((lane >> 4) << 2);
  const int ocol0 = tileN + wc * 64 + lrow;
  float bv[4];
#pragma unroll
  for (int n = 0; n < 4; ++n) bv[n] = bias[ocol0 + n * 16];
#pragma unroll
  for (int m = 0; m < 8; ++m) {
#pragma unroll
    for (int n = 0; n < 4; ++n) {
      size_t base = (size_t)(orow + m * 16) * N_DIM + (ocol0 + n * 16);
#pragma unroll
      for (int r = 0; r < 4; ++r)
        C[base + (size_t)r * N_DIM] = acc[m][n][r] + bv[n];
    }
  }
}

extern "C" void kernel_launch(void* const* d_in, const int* in_sizes, int n_in,
                              void* d_out, int out_size, void* d_ws, size_t ws_size,
                              hipStream_t stream) {
  const float* x = (const float*)d_in[0];
  const float* cc = (const float*)d_in[1];
  const int* cl = (const int*)d_in[2];
  const float* rc = (const float*)d_in[3];
  const int* rl = (const int*)d_in[4];
  const float* bias = (const float*)d_in[5];
  float* out = (float*)d_out;

  ushort_t* Wbf = (ushort_t*)d_ws;                                  // 32 MB
  ushort_t* Xbf = (ushort_t*)d_ws + (size_t)N_DIM * K_DIM;          // 64 MB

  (void)hipFuncSetAttribute((const void*)gemm_bf16,
                            hipFuncAttributeMaxDynamicSharedMemorySize, SMEM_BYTES);

  dequant_w<<<NBLOCKS_VQ / 256, 256, 0, stream>>>(cc, cl, rc, rl, Wbf);
  cvt_x_bf16<<<(int)((M_DIM * (size_t)K_DIM / 8) / 256), 256, 0, stream>>>(x, Xbf);
  gemm_bf16<<<(M_DIM / BM) * (N_DIM / BN), THREADS, SMEM_BYTES, stream>>>(Xbf, Wbf, bias, out);
}

// Round 4
// 276.972 us; speedup vs baseline: 1.0811x; 1.0811x over previous
//
#include <hip/hip_runtime.h>
#include <hip/hip_bf16.h>
#include <stdint.h>

#define M_DIM 8192
#define N_DIM 4096
#define K_DIM 4096
#define BM 256
#define BN 256
#define BKQ 32
#define NT (K_DIM / BKQ)   // 128 K-steps
#define THREADS 512
#define NBLOCKS_VQ (N_DIM * K_DIM / 16)

#define ATILE_B 16384      // one A (or B) K-tile: 256 rows x 32 cols x 2B
#define BOFF    65536      // B buffers start at 64KB
#define SMEM_BYTES 131072

typedef short bf16x8 __attribute__((ext_vector_type(8)));
typedef float f32x4 __attribute__((ext_vector_type(4)));
typedef unsigned short ushort_t;
typedef ushort_t ushort8 __attribute__((ext_vector_type(8)));

#define GLOBAL_AS __attribute__((address_space(1)))
#define LDS_AS __attribute__((address_space(3)))

__device__ __forceinline__ ushort_t f2bf(float f) {
  union { float f; uint32_t u; } v; v.f = f;
  uint32_t u = v.u;
  return (ushort_t)((u + 0x7FFFu + ((u >> 16) & 1u)) >> 16);
}

// ---------------- dequant: W[j][k] = coarse[cl[b]] + res[rl[b]], block b of 16 elems
__global__ __launch_bounds__(256) void dequant_w(
    const float* __restrict__ cc, const int* __restrict__ cl,
    const float* __restrict__ rc, const int* __restrict__ rl,
    ushort_t* __restrict__ wout) {
  int b = blockIdx.x * 256 + threadIdx.x;
  int ci = cl[b];
  int ri = rl[b];
  const float4* c4 = (const float4*)(cc + (size_t)ci * 16);
  const float4* r4 = (const float4*)(rc + (size_t)ri * 16);
  float s[16];
#pragma unroll
  for (int p = 0; p < 4; ++p) {
    float4 a = c4[p];
    float4 r = r4[p];
    s[p * 4 + 0] = a.x + r.x;
    s[p * 4 + 1] = a.y + r.y;
    s[p * 4 + 2] = a.z + r.z;
    s[p * 4 + 3] = a.w + r.w;
  }
  ushort8 o0, o1;
#pragma unroll
  for (int j = 0; j < 8; ++j) o0[j] = f2bf(s[j]);
#pragma unroll
  for (int j = 0; j < 8; ++j) o1[j] = f2bf(s[8 + j]);
  ushort8* dst = (ushort8*)(wout + (size_t)b * 16);
  dst[0] = o0;
  dst[1] = o1;
}

// ---------------- x fp32 -> bf16
__global__ __launch_bounds__(256) void cvt_x_bf16(const float* __restrict__ x,
                                                  ushort_t* __restrict__ xb) {
  size_t i = (size_t)blockIdx.x * 256 + threadIdx.x;  // 8 elems each
  const float4* p = (const float4*)x + i * 2;
  float4 a = p[0];
  float4 b = p[1];
  ushort8 o;
  o[0] = f2bf(a.x); o[1] = f2bf(a.y); o[2] = f2bf(a.z); o[3] = f2bf(a.w);
  o[4] = f2bf(b.x); o[5] = f2bf(b.y); o[6] = f2bf(b.z); o[7] = f2bf(b.w);
  ((ushort8*)xb)[i] = o;
}

// stage one K-tile (A 256x32 + B 256x32 bf16) into buffer `buf`.
// gA0/gB0 are per-thread q=0 source pointers (already inverse-swizzle-adjusted).
__device__ __forceinline__ void stage_tile(char* smem,
    const ushort_t* gA0, const ushort_t* gB0,
    int ldsA0, int ldsB0, int tile, int buf) {
  const ushort_t* ga = gA0 + (size_t)tile * BKQ;
  const ushort_t* gb = gB0 + (size_t)tile * BKQ;
  char* la = smem + buf * ATILE_B + ldsA0;
  char* lb = smem + BOFF + buf * ATILE_B + ldsB0;
  __builtin_amdgcn_global_load_lds((const GLOBAL_AS void*)ga,
                                   (LDS_AS void*)la, 16, 0, 0);
  __builtin_amdgcn_global_load_lds((const GLOBAL_AS void*)(ga + (size_t)128 * K_DIM),
                                   (LDS_AS void*)(la + 8192), 16, 0, 0);
  __builtin_amdgcn_global_load_lds((const GLOBAL_AS void*)gb,
                                   (LDS_AS void*)lb, 16, 0, 0);
  __builtin_amdgcn_global_load_lds((const GLOBAL_AS void*)(gb + (size_t)128 * K_DIM),
                                   (LDS_AS void*)(lb + 8192), 16, 0, 0);
}

template<int VM, bool ISSUE>
__device__ __forceinline__ void kstep(char* smem,
    const ushort_t* gA0, const ushort_t* gB0, int ldsA0, int ldsB0,
    int aoff, int boff, f32x4 (&acc)[8][4], int t, int buf) {
  // counted vmcnt: tile t's 4 loads (issued 3 steps ago) done; t+1,t+2 in flight
  if constexpr (VM == 8) asm volatile("s_waitcnt vmcnt(8)" ::: "memory");
  else if constexpr (VM == 4) asm volatile("s_waitcnt vmcnt(4)" ::: "memory");
  else asm volatile("s_waitcnt vmcnt(0)" ::: "memory");
  __builtin_amdgcn_s_barrier();          // raw barrier: no vmcnt(0) drain
  __builtin_amdgcn_sched_barrier(0);     // pin: nothing hoists above the barrier
  if constexpr (ISSUE)
    stage_tile(smem, gA0, gB0, ldsA0, ldsB0, t + 3, (buf + 3) & 3);

  const ushort_t* aB = (const ushort_t*)(smem + buf * ATILE_B) + aoff;
  const ushort_t* bB = (const ushort_t*)(smem + BOFF + buf * ATILE_B) + boff;

  bf16x8 b[4], a[4];
#pragma unroll
  for (int n = 0; n < 4; ++n) b[n] = *(const bf16x8*)(bB + n * 512);
#pragma unroll
  for (int m = 0; m < 4; ++m) a[m] = *(const bf16x8*)(aB + m * 512);
  __builtin_amdgcn_s_setprio(1);
#pragma unroll
  for (int m = 0; m < 4; ++m)
#pragma unroll
    for (int n = 0; n < 4; ++n)
      acc[m][n] = __builtin_amdgcn_mfma_f32_16x16x32_bf16(a[m], b[n], acc[m][n], 0, 0, 0);
  __builtin_amdgcn_s_setprio(0);
#pragma unroll
  for (int m = 0; m < 4; ++m) a[m] = *(const bf16x8*)(aB + 2048 + m * 512);
  __builtin_amdgcn_s_setprio(1);
#pragma unroll
  for (int m = 0; m < 4; ++m)
#pragma unroll
    for (int n = 0; n < 4; ++n)
      acc[m + 4][n] = __builtin_amdgcn_mfma_f32_16x16x32_bf16(a[m], b[n], acc[m + 4][n], 0, 0, 0);
  __builtin_amdgcn_s_setprio(0);
}

// C[M][N] = A[M][K] * B[N][K]^T + bias; 256x256 tile, BK=32, 4-deep pipeline.
// LDS swizzle: 16B-slot ^= (row>>1)&3  -> with 64B rows (bank-start =
// 16*(row&1) + 4*slot) every 8 consecutive rows at a fixed k-group hit 8
// distinct bank-quads => ds_read_b128 at the 8-clock floor.
__global__ __launch_bounds__(THREADS, 2) void gemm_bf16(
    const ushort_t* __restrict__ A, const ushort_t* __restrict__ B,
    const float* __restrict__ bias, float* __restrict__ C) {
  extern __shared__ char smem[];

  const int nwg = (M_DIM / BM) * (N_DIM / BN);  // 512, %8==0 -> bijective swizzle
  int bid = blockIdx.x;
  int swz = (bid & 7) * (nwg >> 3) + (bid >> 3);
  int bx = swz & 15;            // 16 N-tiles
  int by = swz >> 4;            // 32 M-tiles
  const int tileM = by * BM;
  const int tileN = bx * BN;

  const int tid = threadIdx.x;
  const int lane = tid & 63;
  const int wave = tid >> 6;
  const int wr = wave >> 1;     // 0..3? no: 8 waves as 2M x 4N
  const int wrM = wave >> 2;    // 0..1 -> M offset wrM*128
  const int wcN = wave & 3;     // 0..3 -> N offset wcN*64
  (void)wr;

  // staging: LDS linear chunk tid -> row tid>>2, slot tid&3; inverse swizzle:
  // source col group = slot ^ ((row>>1)&3)
  int srow = tid >> 2;          // 0..127 (round adds 128; 128>>1 ≡ 0 mod 4)
  int slot = tid & 3;
  int scol = ((slot ^ ((srow >> 1) & 3)) << 3);
  const ushort_t* gA0 = A + (size_t)(tileM + srow) * K_DIM + scol;
  const ushort_t* gB0 = B + (size_t)(tileN + srow) * K_DIM + scol;
  const int ldsA0 = wave << 10;  // wave-uniform base; HW appends lane*16
  const int ldsB0 = wave << 10;

  // fragment read offsets: k-slot g ^= (row>>1)&3 (row offsets ≡0 mod 16)
  const int lrow = lane & 15;
  const int g8 = (lane >> 4) << 3;                     // 0,8,16,24
  const int ksw = g8 ^ (((lrow >> 1) & 3) << 3);       // swizzled k elem-offset
  const int aoff = (wrM * 128 + lrow) * BKQ + ksw;
  const int boff = (wcN * 64 + lrow) * BKQ + ksw;

  f32x4 acc[8][4];
#pragma unroll
  for (int m = 0; m < 8; ++m)
#pragma unroll
    for (int n = 0; n < 4; ++n) acc[m][n] = (f32x4)0.0f;

  // prologue: fill pipeline with tiles 0..2
  stage_tile(smem, gA0, gB0, ldsA0, ldsB0, 0, 0);
  stage_tile(smem, gA0, gB0, ldsA0, ldsB0, 1, 1);
  stage_tile(smem, gA0, gB0, ldsA0, ldsB0, 2, 2);

  for (int tb = 0; tb < 31; ++tb) {   // t = 0..123
    int t = tb << 2;
    kstep<8, true>(smem, gA0, gB0, ldsA0, ldsB0, aoff, boff, acc, t + 0, 0);
    kstep<8, true>(smem, gA0, gB0, ldsA0, ldsB0, aoff, boff, acc, t + 1, 1);
    kstep<8, true>(smem, gA0, gB0, ldsA0, ldsB0, aoff, boff, acc, t + 2, 2);
    kstep<8, true>(smem, gA0, gB0, ldsA0, ldsB0, aoff, boff, acc, t + 3, 3);
  }
  kstep<8, true >(smem, gA0, gB0, ldsA0, ldsB0, aoff, boff, acc, 124, 0);  // stages 127
  kstep<8, false>(smem, gA0, gB0, ldsA0, ldsB0, aoff, boff, acc, 125, 1);
  kstep<4, false>(smem, gA0, gB0, ldsA0, ldsB0, aoff, boff, acc, 126, 2);
  kstep<0, false>(smem, gA0, gB0, ldsA0, ldsB0, aoff, boff, acc, 127, 3);

  // epilogue: C/D layout col = lane&15, row = (lane>>4)*4 + reg
  const int orow = tileM + wrM * 128 + ((lane >> 4) << 2);
  const int ocol0 = tileN + wcN * 64 + lrow;
  float bv[4];
#pragma unroll
  for (int n = 0; n < 4; ++n) bv[n] = bias[ocol0 + n * 16];
#pragma unroll
  for (int m = 0; m < 8; ++m) {
#pragma unroll
    for (int n = 0; n < 4; ++n) {
      size_t base = (size_t)(orow + m * 16) * N_DIM + (ocol0 + n * 16);
#pragma unroll
      for (int r = 0; r < 4; ++r)
        C[base + (size_t)r * N_DIM] = acc[m][n][r] + bv[n];
    }
  }
}

extern "C" void kernel_launch(void* const* d_in, const int* in_sizes, int n_in,
                              void* d_out, int out_size, void* d_ws, size_t ws_size,
                              hipStream_t stream) {
  const float* x = (const float*)d_in[0];
  const float* cc = (const float*)d_in[1];
  const int* cl = (const int*)d_in[2];
  const float* rc = (const float*)d_in[3];
  const int* rl = (const int*)d_in[4];
  const float* bias = (const float*)d_in[5];
  float* out = (float*)d_out;

  ushort_t* Wbf = (ushort_t*)d_ws;                                  // 32 MB
  ushort_t* Xbf = (ushort_t*)d_ws + (size_t)N_DIM * K_DIM;          // 64 MB

  (void)hipFuncSetAttribute((const void*)gemm_bf16,
                            hipFuncAttributeMaxDynamicSharedMemorySize, SMEM_BYTES);

  dequant_w<<<NBLOCKS_VQ / 256, 256, 0, stream>>>(cc, cl, rc, rl, Wbf);
  cvt_x_bf16<<<(int)((M_DIM * (size_t)K_DIM / 8) / 256), 256, 0, stream>>>(x, Xbf);
  gemm_bf16<<<(M_DIM / BM) * (N_DIM / BN), THREADS, SMEM_BYTES, stream>>>(Xbf, Wbf, bias, out);
}